// Round 4
// baseline (1786.409 us; speedup 1.0000x reference)
//
#include <hip/hip_runtime.h>
#include <cstdint>

// Problem constants (match reference)
#define BATCH 32
#define CIN   64
#define T_IN  8192
#define K1    50
#define K2    100
#define CPC   5
#define T1    8143           // T_IN - K1 + 1
#define T2    8044           // T1 - K2 + 1

// Tiling
#define TO    2048           // output times per block
#define NTB   4              // ceil(T2 / TO) -> 4*2048 = 8192 >= 8044
#define YLEN  (TO + K2 - 1)  // 2147 y values needed per tile
#define YPAD  2148           // row stride (multiple of 4 for float4)
#define XLEN  (TO + K1 + K2 - 2) // 2196 x values needed per tile
#define XPAD  2208           // padded/zero-filled (window overshoot safe)

__global__ __launch_bounds__(256, 2)
void envdet_f32_kernel(const float* __restrict__ x,
                       const float* __restrict__ w1,
                       const float* __restrict__ b1,
                       const float* __restrict__ w2,
                       const float* __restrict__ b2,
                       float* __restrict__ z)
{
    __shared__ __align__(16) float sh_x[XPAD];
    __shared__ __align__(16) float sh_y[5 * YPAD];
    __shared__ __align__(16) float sh_w2[2500];
    __shared__ __align__(16) float sh_w1[5 * 52];   // k padded 50 -> 52 with zeros

    const int tid = threadIdx.x;
    const int tb  = blockIdx.x;   // time tile
    const int g   = blockIdx.y;   // group (input channel)
    const int b   = blockIdx.z;   // batch
    const int t0  = tb * TO;

    // ---- stage inputs into LDS (coalesced) ----
    const float* xg = x + ((size_t)b * CIN + g) * T_IN;
    for (int i = tid; i < XPAD; i += 256) {
        const int xi = t0 + i;
        sh_x[i] = (i < XLEN && xi < T_IN) ? xg[xi] : 0.0f;
    }
    const float* w2g = w2 + (size_t)g * (CPC * CPC * K2);  // 2500 contiguous
    for (int i = tid; i < CPC * CPC * K2; i += 256) sh_w2[i] = w2g[i];
    const float* w1g = w1 + (size_t)g * (CPC * K1);        // 250 contiguous
    for (int i = tid; i < 5 * 52; i += 256) {
        const int c = i / 52, k = i - c * 52;
        sh_w1[i] = (k < K1) ? w1g[c * K1 + k] : 0.0f;
    }
    __syncthreads();

    // ---- phase 1: y[c][j] = |b1[c] + sum_k w1[c][k] * x[j+k]|, j in [0, YLEN) ----
    // thread owns 8 consecutive j; float4 LDS reads (lane stride 16B, conflict-free)
    #pragma unroll 1
    for (int c = 0; c < CPC; ++c) {
        const float bias = b1[g * CPC + c];
        const float4* w1v = (const float4*)(sh_w1 + c * 52);
        float* yc = sh_y + c * YPAD;
        #pragma unroll 1
        for (int r = 0; r < 2; ++r) {
            const int j0 = 8 * tid + 2048 * r;
            if (j0 >= YLEN) break;
            float a[8];
            #pragma unroll
            for (int d = 0; d < 8; ++d) a[d] = bias;
            #pragma unroll
            for (int k4 = 0; k4 < 13; ++k4) {
                const float4 w  = w1v[k4];
                const float4 x0 = *(const float4*)(sh_x + j0 + 4 * k4);
                const float4 x1 = *(const float4*)(sh_x + j0 + 4 * k4 + 4);
                const float4 x2 = *(const float4*)(sh_x + j0 + 4 * k4 + 8);
                const float xs[12] = {x0.x,x0.y,x0.z,x0.w, x1.x,x1.y,x1.z,x1.w,
                                      x2.x,x2.y,x2.z,x2.w};
                #pragma unroll
                for (int d = 0; d < 8; ++d)
                    a[d] = fmaf(w.x, xs[d],   fmaf(w.y, xs[d+1],
                           fmaf(w.z, xs[d+2], fmaf(w.w, xs[d+3], a[d]))));
            }
            if (j0 + 7 < YLEN) {
                *(float4*)(yc + j0)     = make_float4(fabsf(a[0]), fabsf(a[1]), fabsf(a[2]), fabsf(a[3]));
                *(float4*)(yc + j0 + 4) = make_float4(fabsf(a[4]), fabsf(a[5]), fabsf(a[6]), fabsf(a[7]));
            } else {
                #pragma unroll
                for (int d = 0; d < 8; ++d)
                    if (j0 + d < YLEN) yc[j0 + d] = fabsf(a[d]);
            }
        }
    }
    __syncthreads();

    // ---- phase 2: z[oc][i] = b2[oc] + sum_{c,k} w2[oc][c][k] * y[c][i+k] ----
    // thread owns times i0+{0..3} and i0+1024+{0..3}; 40 accumulators
    float acc[CPC][8];
    #pragma unroll
    for (int oc = 0; oc < CPC; ++oc) {
        const float bias = b2[g * CPC + oc];
        #pragma unroll
        for (int d = 0; d < 8; ++d) acc[oc][d] = bias;
    }

    const int i0 = 4 * tid;
    const float4* w2v = (const float4*)sh_w2;
    #pragma unroll 1
    for (int c = 0; c < CPC; ++c) {
        const float* yc = sh_y + c * YPAD;
        #pragma unroll 2
        for (int k4 = 0; k4 < 25; ++k4) {
            float4 wv[CPC];
            #pragma unroll
            for (int oc = 0; oc < CPC; ++oc)
                wv[oc] = w2v[(oc * CPC + c) * 25 + k4];   // uniform -> LDS broadcast
            #pragma unroll
            for (int rg = 0; rg < 2; ++rg) {
                const int yb = i0 + 1024 * rg + 4 * k4;
                const float4 ya = *(const float4*)(yc + yb);
                const float4 yb4 = *(const float4*)(yc + yb + 4);
                const float ys[8] = {ya.x,ya.y,ya.z,ya.w, yb4.x,yb4.y,yb4.z,yb4.w};
                #pragma unroll
                for (int oc = 0; oc < CPC; ++oc) {
                    #pragma unroll
                    for (int d = 0; d < 4; ++d) {
                        acc[oc][4*rg + d] =
                            fmaf(wv[oc].x, ys[d],
                            fmaf(wv[oc].y, ys[d+1],
                            fmaf(wv[oc].z, ys[d+2],
                            fmaf(wv[oc].w, ys[d+3], acc[oc][4*rg + d]))));
                    }
                }
            }
        }
    }

    // ---- store (float4, fully coalesced; T2 % 4 == 0 so no partial vectors) ----
    float* zb = z + (size_t)b * (320 * (size_t)T2);
    #pragma unroll
    for (int oc = 0; oc < CPC; ++oc) {
        float* zc = zb + (size_t)(g * CPC + oc) * T2;
        #pragma unroll
        for (int rg = 0; rg < 2; ++rg) {
            const int i = t0 + i0 + 1024 * rg;
            if (i < T2)
                *(float4*)(zc + i) = make_float4(acc[oc][4*rg+0], acc[oc][4*rg+1],
                                                 acc[oc][4*rg+2], acc[oc][4*rg+3]);
        }
    }
}

extern "C" void kernel_launch(void* const* d_in, const int* in_sizes, int n_in,
                              void* d_out, int out_size, void* d_ws, size_t ws_size,
                              hipStream_t stream) {
    (void)in_sizes; (void)n_in; (void)d_ws; (void)ws_size; (void)out_size;
    const float* x  = (const float*)d_in[0];
    const float* w1 = (const float*)d_in[1];
    const float* b1 = (const float*)d_in[2];
    const float* w2 = (const float*)d_in[3];
    const float* b2 = (const float*)d_in[4];
    float* z = (float*)d_out;

    dim3 grid(NTB, CIN, BATCH);   // (time tiles, groups, batch)
    envdet_f32_kernel<<<grid, 256, 0, stream>>>(x, w1, b1, w2, b2, z);
}

// Round 14
// 893.624 us; speedup vs baseline: 1.9991x; 1.9991x over previous
//
#include <hip/hip_runtime.h>
#include <cstdint>

// ---- problem constants ----
#define BATCH 32
#define CIN   64
#define TIN   8192
#define K1    50
#define K2    100
#define CPC   5
#define T1    8143
#define T2    8044
#define NOC   320

// ---- tiling ----
// Block = (group g, 128 output times). Both convs as MFMA GEMMs:
//   N-axis = batch (32 = 2 halves of 16), M-axis = (chan, shift s in 0..7) = 40 rows in 3 sets of 16,
//   K-axis = extended taps k' (conv2: [0,128) -> 4 chunks; conv1: [0,64) -> 2 chunks),
//   bases step 8 => every LDS fragment load is a 16B-aligned b128. A[k'-s] zero-padded.
#define TT    128
#define NTILE 63             // ceil(8044/128)
#define NU1   29             // conv1 bases: tau = 8u'+s covers [0,232)
#define YSTR  248            // y stride per (c,b), mult of 8; reads reach 8*15+127=247
#define YB    (32*YSTR)      // 7936 elems per c
#define XSTR  296            // x stride per b; reads reach 8*28+63=287; 296 avoids 2-bank LDS camp
#define XTOT  (32*XSTR)      // 9472 elems
#define DSTR  130            // D transpose buffer stride (f32)

// ---- LDS layout (bytes); region after y is time-multiplexed ----
#define OFF_Y   0                     // bf16 y[5][32][YSTR]            79360 B   (phase1 W, phase2 R)
#define OFF_BUF 79360
#define OFF_X   OFF_BUF               // bf16 x[32][XSTR]               18944 B   (phase1)
#define OFF_A1  (OFF_BUF + 18944)     // bf16 A1[3][2][64][8]            6144 B   (phase1)
#define OFF_A2  OFF_BUF               // bf16 A2[3][5][4][64][8]        61440 B   (phase2, after barrier)
#define OFF_D   OFF_BUF               // f32  D[32*5][DSTR]             83200 B   (epilogue, after barrier)
#define LDS_TOTAL 162560              // 79360 + 83200  (<= 163840)

typedef __attribute__((ext_vector_type(8))) short short8v;   // 8 x bf16 (guide-verified frag type)
typedef __attribute__((ext_vector_type(4))) float float4v;

__device__ inline ushort f32_bf16(float f) {
    union { float f; uint32_t u; } v; v.f = f;
    uint32_t u = v.u;
    return (ushort)((u + 0x7FFFu + ((u >> 16) & 1u)) >> 16);   // RNE
}

__global__ __launch_bounds__(512, 1)
void envdet_mfma(const float* __restrict__ x,
                 const float* __restrict__ w1,
                 const float* __restrict__ b1,
                 const float* __restrict__ w2,
                 const float* __restrict__ b2,
                 float* __restrict__ z)
{
    extern __shared__ char smem[];
    ushort* y16 = (ushort*)(smem + OFF_Y);
    ushort* x16 = (ushort*)(smem + OFF_X);
    ushort* a1  = (ushort*)(smem + OFF_A1);
    ushort* a2  = (ushort*)(smem + OFF_A2);
    float*  dls = (float*)(smem + OFF_D);

    const int tid  = threadIdx.x;
    const int g    = blockIdx.y;
    const int i0   = blockIdx.x * TT;

    const int lane = tid & 63;
    const int wv   = tid >> 6;         // wave 0..7
    const int n16  = lane & 15;        // MFMA col index (batch within half)
    const int hh   = lane >> 4;        // 0..3 (k-subblock for A/B, row-block for D)
    const int bh   = wv & 1;           // batch half
    const int uq   = wv >> 1;          // base quarter 0..3
    const int bb   = n16 + 16*bh;      // batch 0..31

    const float* xg  = x  + (size_t)g * TIN;
    const float* w1g = w1 + (size_t)g * (CPC*K1);
    const float* w2g = w2 + (size_t)g * (CPC*CPC*K2);

    // ---- stage x -> bf16 LDS; zero y tail; build A1 ----
    for (int idx = tid; idx < XTOT; idx += 512) {
        int b  = idx / XSTR;
        int t  = idx - b * XSTR;
        int gt = i0 + t;
        float v = (gt < TIN) ? xg[(size_t)b * (size_t)(CIN*TIN) + gt] : 0.0f;
        x16[idx] = f32_bf16(v);
    }
    for (int idx = tid; idx < 5*32*16; idx += 512) {        // y[*][*][232..248) = 0 (never hit by nonzero A)
        int cb = idx >> 4;
        y16[cb * YSTR + 232 + (idx & 15)] = 0;
    }
    {   // A1[(sg,kc)][lane][j] = w1[c][k-s],  R=16sg+(lane&15)=c*8+s, k=32kc+8h+j
        int l = tid >> 3, j = tid & 7;
        int m = l & 15, h = l >> 4;
        #pragma unroll
        for (int sg = 0; sg < 3; ++sg)
        #pragma unroll
        for (int kc = 0; kc < 2; ++kc) {
            int R = 16*sg + m;
            int k = 32*kc + 8*h + j;
            int c = R >> 3, s = R & 7;
            int kk = k - s;
            ushort val = 0;
            if (R < 40 && kk >= 0 && kk < K1) val = f32_bf16(w1g[c*K1 + kk]);
            a1[((sg*2 + kc)*64 + l)*8 + j] = val;
        }
    }
    __syncthreads();

    // ---- phase 1: conv1 MFMA.  D[(c,s)][b] at base 8u' -> y[c][b][8u'+s] = |D + b1[c]| ----
    for (int q = 0; q < 8; ++q) {
        int up = uq + 4*q;
        if (up >= NU1) break;
        float4v acc0 = {0,0,0,0}, acc1 = {0,0,0,0}, acc2 = {0,0,0,0};
        #pragma unroll
        for (int kc = 0; kc < 2; ++kc) {
            const short8v bx  = *(const short8v*)(x16 + bb*XSTR + 8*up + 32*kc + 8*hh);
            const short8v fa0 = *(const short8v*)(a1 + ((0*2+kc)*64 + lane)*8);
            const short8v fa1 = *(const short8v*)(a1 + ((1*2+kc)*64 + lane)*8);
            const short8v fa2 = *(const short8v*)(a1 + ((2*2+kc)*64 + lane)*8);
            acc0 = __builtin_amdgcn_mfma_f32_16x16x32_bf16(fa0, bx, acc0, 0,0,0);
            acc1 = __builtin_amdgcn_mfma_f32_16x16x32_bf16(fa1, bx, acc1, 0,0,0);
            acc2 = __builtin_amdgcn_mfma_f32_16x16x32_bf16(fa2, bx, acc2, 0,0,0);
        }
        #pragma unroll
        for (int sg = 0; sg < 3; ++sg) {
            float4v av = (sg==0) ? acc0 : ((sg==1) ? acc1 : acc2);
            #pragma unroll
            for (int r = 0; r < 4; ++r) {
                int R = 16*sg + 4*hh + r;         // D row = 4*(lane>>4)+r  [m89-verified]
                if (R < 40) {
                    int c = R >> 3, s = R & 7;
                    float val = fabsf(av[r] + b1[g*CPC + c]);
                    y16[(c*32 + bb)*YSTR + 8*up + s] = f32_bf16(val);
                }
            }
        }
    }
    __syncthreads();

    // ---- build A2 over dead x/A1 region ----
    {   // A2[(sg,cc,kc)][lane][j] = w2[oc][cc][k'-s], R=16sg+(lane&15)=oc*8+s, k'=32kc+8h+j
        int l = tid >> 3, j = tid & 7;
        int m = l & 15, h = l >> 4;
        for (int cc = 0; cc < 5; ++cc)
        #pragma unroll
        for (int sg = 0; sg < 3; ++sg)
        #pragma unroll
        for (int kc = 0; kc < 4; ++kc) {
            int R  = 16*sg + m;
            int kp = 32*kc + 8*h + j;
            int oc = R >> 3, s = R & 7;
            int kk = kp - s;
            ushort val = 0;
            if (R < 40 && kk >= 0 && kk < K2) val = f32_bf16(w2g[(oc*CPC + cc)*K2 + kk]);
            a2[(((sg*5 + cc)*4 + kc)*64 + l)*8 + j] = val;
        }
    }
    __syncthreads();

    // ---- phase 2: conv2 MFMA.  acc[du][sg] over (cc,kc); B-frag feeds 3 sets ----
    float4v acc[4][3];
    #pragma unroll
    for (int du = 0; du < 4; ++du)
        #pragma unroll
        for (int sg = 0; sg < 3; ++sg) acc[du][sg] = (float4v){0,0,0,0};

    for (int cc = 0; cc < 5; ++cc) {
        #pragma unroll
        for (int kc = 0; kc < 4; ++kc) {
            const short8v fa0 = *(const short8v*)(a2 + (((0*5+cc)*4 + kc)*64 + lane)*8);
            const short8v fa1 = *(const short8v*)(a2 + (((1*5+cc)*4 + kc)*64 + lane)*8);
            const short8v fa2 = *(const short8v*)(a2 + (((2*5+cc)*4 + kc)*64 + lane)*8);
            #pragma unroll
            for (int du = 0; du < 4; ++du) {
                int u = 4*uq + du;
                const short8v by = *(const short8v*)(y16 + (cc*32 + bb)*YSTR + 8*u + 32*kc + 8*hh);
                acc[du][0] = __builtin_amdgcn_mfma_f32_16x16x32_bf16(fa0, by, acc[du][0], 0,0,0);
                acc[du][1] = __builtin_amdgcn_mfma_f32_16x16x32_bf16(fa1, by, acc[du][1], 0,0,0);
                acc[du][2] = __builtin_amdgcn_mfma_f32_16x16x32_bf16(fa2, by, acc[du][2], 0,0,0);
            }
        }
    }
    __syncthreads();   // y/A2 reads complete before D overwrites

    // ---- epilogue: D -> LDS transpose (add bias), then coalesced f32 stores ----
    #pragma unroll
    for (int du = 0; du < 4; ++du) {
        int u = 4*uq + du;
        #pragma unroll
        for (int sg = 0; sg < 3; ++sg) {
            #pragma unroll
            for (int r = 0; r < 4; ++r) {
                int R = 16*sg + 4*hh + r;
                if (R < 40) {
                    int oc = R >> 3, s = R & 7;
                    dls[(bb*5 + oc)*DSTR + 8*u + s] = acc[du][sg][r] + b2[g*CPC + oc];
                }
            }
        }
    }
    __syncthreads();

    for (int idx = tid; idx < 32*5*TT; idx += 512) {
        int i   = idx & (TT-1);
        int row = idx >> 7;            // b*5 + oc
        int b   = row / 5;
        int oc  = row - 5*b;
        int gi  = i0 + i;
        if (gi < T2)
            z[((size_t)b*NOC + (size_t)(g*CPC + oc))*T2 + gi] = dls[row*DSTR + i];
    }
}

extern "C" void kernel_launch(void* const* d_in, const int* in_sizes, int n_in,
                              void* d_out, int out_size, void* d_ws, size_t ws_size,
                              hipStream_t stream) {
    (void)in_sizes; (void)n_in; (void)d_ws; (void)ws_size; (void)out_size;
    const float* x  = (const float*)d_in[0];
    const float* w1 = (const float*)d_in[1];
    const float* b1 = (const float*)d_in[2];
    const float* w2 = (const float*)d_in[3];
    const float* b2 = (const float*)d_in[4];
    float* z = (float*)d_out;

    // >64KB dynamic LDS (162560B); 128KB workgroups proven on gfx950 (m201).
    (void)hipFuncSetAttribute((const void*)envdet_mfma,
                              hipFuncAttributeMaxDynamicSharedMemorySize, LDS_TOTAL);
    envdet_mfma<<<dim3(NTILE, CIN), 512, LDS_TOTAL, stream>>>(x, w1, b1, w2, b2, z);
}